// Round 5
// baseline (163.675 us; speedup 1.0000x reference)
//
#include <hip/hip_runtime.h>
#include <math.h>

#define IMG_H 512
#define IMG_W 512
#define NIMG 32
#define B_ROWS 8        // rows per block in pass 1: 4 waves x 2 rows each
#define RB_W 552        // rowbuf padded width; cmax x -> index 20+x, halo [0..19] & [532..551]
#define T5_W 544        // tmp5 padded width (542 used, 2 tail slots never read)
#define YC2 32          // output rows per block in pass 2

// ---------------- Pass 1: cmax + horizontal win35, barrier-free + 2-row pipeline ------
// Each wave owns TWO rows (A,B), one LDS rowbuf/tmp5 pair reused. Row B's global loads
// are issued immediately after row A's LDS fill, so B's HBM latency hides under A's
// win5/win35 compute (the one-shot version stalled its full load latency at the first
// lgkmcnt drain with nothing to overlap). Still zero s_barrier: all cross-lane LDS flow
// is within-wave, ordered by s_waitcnt lgkmcnt(0) + sched_barrier(0) (rule #18).
__global__ __launch_bounds__(256) void dc_rowmax(const float* __restrict__ img,
                                                 float* __restrict__ rowmax) {
    __shared__ float rowbuf[4][RB_W];
    __shared__ float tmp5[4][T5_W];
    const int b = blockIdx.x;            // n*64 + ytile
    const int n = b >> 6;
    const int y0 = (b & 63) * B_ROWS;
    const int tid = (int)threadIdx.x;
    const int lane = tid & 63;
    const int wv = tid >> 6;
    const int yA = y0 + 2 * wv;          // wave's rows: yA, yA+1

    // halo pads written once, valid for both rows (fill never overwrites them)
    if (lane < 40) {
        int idx = (lane < 20) ? lane : (512 + lane);   // [0,20) and [532,552)
        rowbuf[wv][idx] = -INFINITY;
    }

    const float4* imgA = (const float4*)(img + ((size_t)n * 3 * IMG_H + yA) * IMG_W);
    const float4* imgB = imgA + (IMG_W / 4);           // row yA+1 (contiguous in channel)

    // ---- row A loads (6 x dwordx4) ----
    float4 Aa0 = imgA[lane],          Aa1 = imgA[lane + 64];
    float4 Ab0 = imgA[65536 + lane],  Ab1 = imgA[65536 + lane + 64];
    float4 Ac0 = imgA[131072 + lane], Ac1 = imgA[131072 + lane + 64];
    // cmax(row A) -> rowbuf
    {
        float4 m0, m1;
        m0.x = 1.0f - fminf(Aa0.x, fminf(Ab0.x, Ac0.x));
        m0.y = 1.0f - fminf(Aa0.y, fminf(Ab0.y, Ac0.y));
        m0.z = 1.0f - fminf(Aa0.z, fminf(Ab0.z, Ac0.z));
        m0.w = 1.0f - fminf(Aa0.w, fminf(Ab0.w, Ac0.w));
        m1.x = 1.0f - fminf(Aa1.x, fminf(Ab1.x, Ac1.x));
        m1.y = 1.0f - fminf(Aa1.y, fminf(Ab1.y, Ac1.y));
        m1.z = 1.0f - fminf(Aa1.z, fminf(Ab1.z, Ac1.z));
        m1.w = 1.0f - fminf(Aa1.w, fminf(Ab1.w, Ac1.w));
        *(float4*)&rowbuf[wv][20 + 4 * lane] = m0;
        *(float4*)&rowbuf[wv][20 + 4 * (lane + 64)] = m1;
    }
    // ---- issue row B loads NOW; consumed after row A's win5 (latency hides under it) --
    float4 Bd0 = imgB[lane],          Bd1 = imgB[lane + 64];
    float4 Be0 = imgB[65536 + lane],  Be1 = imgB[65536 + lane + 64];
    float4 Bf0 = imgB[131072 + lane], Bf1 = imgB[131072 + lane + 64];

    asm volatile("s_waitcnt lgkmcnt(0)" ::: "memory");
    __builtin_amdgcn_sched_barrier(0);

    const float4* rb = (const float4*)&rowbuf[wv][0];  // 16B-aligned (552*4B row stride)
    const float4* t5 = (const float4*)&tmp5[wv][0];    // 16B-aligned (544*4B row stride)
    float* orowA = rowmax + ((size_t)n * IMG_H + yA) * IMG_W;

    // win5 macro: tmp5[4q+d] = max(rowbuf[4q+3+d .. 4q+7+d]), d=0..3
#define WIN5_TASK(q)                                                                 \
    {                                                                                \
        float4 w0 = rb[(q)], w1 = rb[(q) + 1], w2 = rb[(q) + 2];                     \
        float f3 = w0.w, f4 = w1.x, f5 = w1.y, f6 = w1.z, f7 = w1.w;                 \
        float f8 = w2.x, f9 = w2.y, f10 = w2.z;                                      \
        float a34 = fmaxf(f3, f4), a45 = fmaxf(f4, f5), a56 = fmaxf(f5, f6);         \
        float a67 = fmaxf(f6, f7), a78 = fmaxf(f7, f8), a89 = fmaxf(f8, f9);         \
        float4 o;                                                                    \
        o.x = fmaxf(fmaxf(a34, a56), f7);                                            \
        o.y = fmaxf(fmaxf(a45, a67), f8);                                            \
        o.z = fmaxf(fmaxf(a56, a78), f9);                                            \
        o.w = fmaxf(fmaxf(a67, a89), f10);                                           \
        *(float4*)&tmp5[wv][4 * (q)] = o;                                            \
    }
    // win35 macro: out[4q+d] = max_k tmp5[4q+d+5k], k=0..6 (9 aligned b128 reads)
#define WIN35_TASK(q, orow)                                                          \
    {                                                                                \
        float wf[36];                                                                \
        _Pragma("unroll")                                                            \
        for (int k = 0; k < 9; ++k) {                                                \
            float4 t = t5[(q) + k];                                                  \
            wf[4 * k + 0] = t.x; wf[4 * k + 1] = t.y;                                \
            wf[4 * k + 2] = t.z; wf[4 * k + 3] = t.w;                                \
        }                                                                            \
        float4 o;                                                                    \
        o.x = fmaxf(fmaxf(fmaxf(wf[0], wf[5]), fmaxf(wf[10], wf[15])),               \
                    fmaxf(fmaxf(wf[20], wf[25]), wf[30]));                           \
        o.y = fmaxf(fmaxf(fmaxf(wf[1], wf[6]), fmaxf(wf[11], wf[16])),               \
                    fmaxf(fmaxf(wf[21], wf[26]), wf[31]));                           \
        o.z = fmaxf(fmaxf(fmaxf(wf[2], wf[7]), fmaxf(wf[12], wf[17])),               \
                    fmaxf(fmaxf(wf[22], wf[27]), wf[32]));                           \
        o.w = fmaxf(fmaxf(fmaxf(wf[3], wf[8]), fmaxf(wf[13], wf[18])),               \
                    fmaxf(fmaxf(wf[23], wf[28]), wf[33]));                           \
        *(float4*)&(orow)[4 * (q)] = o;                                              \
    }

    // win5 row A: 136 quad-tasks over 64 lanes
    WIN5_TASK(lane)
    WIN5_TASK(lane + 64)
    if (lane < 8) WIN5_TASK(lane + 128)

    asm volatile("s_waitcnt lgkmcnt(0)" ::: "memory");   // tmp5 ready; rowbuf reads retired
    __builtin_amdgcn_sched_barrier(0);

    // row B cmax -> rowbuf (safe: row A's rowbuf reads drained above; targets != tmp5).
    // Issued before win35(A) so the writes overlap win35's tmp5 reads on the LDS pipe.
    {
        float4 m0, m1;
        m0.x = 1.0f - fminf(Bd0.x, fminf(Be0.x, Bf0.x));
        m0.y = 1.0f - fminf(Bd0.y, fminf(Be0.y, Bf0.y));
        m0.z = 1.0f - fminf(Bd0.z, fminf(Be0.z, Bf0.z));
        m0.w = 1.0f - fminf(Bd0.w, fminf(Be0.w, Bf0.w));
        m1.x = 1.0f - fminf(Bd1.x, fminf(Be1.x, Bf1.x));
        m1.y = 1.0f - fminf(Bd1.y, fminf(Be1.y, Bf1.y));
        m1.z = 1.0f - fminf(Bd1.z, fminf(Be1.z, Bf1.z));
        m1.w = 1.0f - fminf(Bd1.w, fminf(Be1.w, Bf1.w));
        *(float4*)&rowbuf[wv][20 + 4 * lane] = m0;
        *(float4*)&rowbuf[wv][20 + 4 * (lane + 64)] = m1;
    }

    // win35 row A (reads tmp5 only — no alias with row B's rowbuf writes)
    WIN35_TASK(lane, orowA)
    WIN35_TASK(lane + 64, orowA)

    asm volatile("s_waitcnt lgkmcnt(0)" ::: "memory");   // B's rowbuf ready; A's tmp5 reads retired
    __builtin_amdgcn_sched_barrier(0);

    // win5 row B
    WIN5_TASK(lane)
    WIN5_TASK(lane + 64)
    if (lane < 8) WIN5_TASK(lane + 128)

    asm volatile("s_waitcnt lgkmcnt(0)" ::: "memory");
    __builtin_amdgcn_sched_barrier(0);

    // win35 row B
    float* orowB = orowA + IMG_W;
    WIN35_TASK(lane, orowB)
    WIN35_TASK(lane + 64, orowB)

#undef WIN5_TASK
#undef WIN35_TASK
}

// -------- Pass 2: vertical win35 = win5 (shift ring) o win7-stride-5 (phase rings) ----
// Unchanged from R2/R4: float2 per thread, literal-indexed register rings, 512 blocks.
__global__ __launch_bounds__(256) void dc_colmax(const float* __restrict__ rowmax,
                                                 float* __restrict__ out) {
    __shared__ float wsum[4];
    const int b = blockIdx.x;            // n*16 + yt
    const int yt = b & 15;
    const int n = b >> 4;
    const int x0 = (int)threadIdx.x * 2; // columns x0, x0+1
    const int y0 = yt * YC2;
    const float2* col = (const float2*)(rowmax + (size_t)n * (IMG_H * IMG_W) + x0);

    float G0[5][6], G1[5][6];            // all accesses use literal [P][slot]
    #pragma unroll
    for (int p = 0; p < 5; ++p)
        #pragma unroll
        for (int k = 0; k < 6; ++k) { G0[p][k] = -INFINITY; G1[p][k] = -INFINITY; }

    float a1, a2, a3, a4;                // win5 shift ring, column x0
    float b1, b2, b3, b4;                // win5 shift ring, column x0+1
    float s = 0.0f;

    // prologue: rows gy = y0-17 .. y0-14
    {
        const int gy = y0 - 17;
        float2 v0 = ((unsigned)(gy + 0) < IMG_H) ? col[(size_t)(gy + 0) * (IMG_W / 2)]
                                                 : make_float2(-INFINITY, -INFINITY);
        float2 v1 = ((unsigned)(gy + 1) < IMG_H) ? col[(size_t)(gy + 1) * (IMG_W / 2)]
                                                 : make_float2(-INFINITY, -INFINITY);
        float2 v2 = ((unsigned)(gy + 2) < IMG_H) ? col[(size_t)(gy + 2) * (IMG_W / 2)]
                                                 : make_float2(-INFINITY, -INFINITY);
        float2 v3 = ((unsigned)(gy + 3) < IMG_H) ? col[(size_t)(gy + 3) * (IMG_W / 2)]
                                                 : make_float2(-INFINITY, -INFINITY);
        a1 = v0.x; a2 = v1.x; a3 = v2.x; a4 = v3.x;
        b1 = v0.y; b2 = v1.y; b3 = v2.y; b4 = v3.y;
    }

#define PUSH(P, J, DO_OUT)                                                              \
    {                                                                                   \
        const int gy_ = y0 - 13 + (J);                                                  \
        float2 v_ = ((unsigned)gy_ < IMG_H) ? col[(size_t)gy_ * (IMG_W / 2)]            \
                                            : make_float2(-INFINITY, -INFINITY);        \
        float gA_ = fmaxf(fmaxf(fmaxf(a1, a2), fmaxf(a3, a4)), v_.x);                   \
        float gB_ = fmaxf(fmaxf(fmaxf(b1, b2), fmaxf(b3, b4)), v_.y);                   \
        a1 = a2; a2 = a3; a3 = a4; a4 = v_.x;                                           \
        b1 = b2; b2 = b3; b3 = b4; b4 = v_.y;                                           \
        if (DO_OUT) {                                                                   \
            float oA_ = fmaxf(fmaxf(fmaxf(G0[P][0], G0[P][1]), fmaxf(G0[P][2], G0[P][3])), \
                              fmaxf(fmaxf(G0[P][4], G0[P][5]), gA_));                   \
            float oB_ = fmaxf(fmaxf(fmaxf(G1[P][0], G1[P][1]), fmaxf(G1[P][2], G1[P][3])), \
                              fmaxf(fmaxf(G1[P][4], G1[P][5]), gB_));                   \
            s += fabsf(oA_) + fabsf(oB_);                                               \
        }                                                                               \
        G0[P][0] = G0[P][1]; G0[P][1] = G0[P][2]; G0[P][2] = G0[P][3];                  \
        G0[P][3] = G0[P][4]; G0[P][4] = G0[P][5]; G0[P][5] = gA_;                       \
        G1[P][0] = G1[P][1]; G1[P][1] = G1[P][2]; G1[P][2] = G1[P][3];                  \
        G1[P][3] = G1[P][4]; G1[P][4] = G1[P][5]; G1[P][5] = gB_;                       \
    }

    // warm-up: J = 0..29, no outputs yet
    #pragma unroll
    for (int g5 = 0; g5 < 6; ++g5) {
        const int j0 = 5 * g5;
        PUSH(0, j0 + 0, 0) PUSH(1, j0 + 1, 0) PUSH(2, j0 + 2, 0)
        PUSH(3, j0 + 3, 0) PUSH(4, j0 + 4, 0)
    }
    // steady: J = 30..59 -> outputs y = 0..29
    #pragma unroll
    for (int g5 = 6; g5 < 12; ++g5) {
        const int j0 = 5 * g5;
        PUSH(0, j0 + 0, 1) PUSH(1, j0 + 1, 1) PUSH(2, j0 + 2, 1)
        PUSH(3, j0 + 3, 1) PUSH(4, j0 + 4, 1)
    }
    // tail: J = 60, 61 -> outputs y = 30, 31
    PUSH(0, 60, 1)
    PUSH(1, 61, 1)
#undef PUSH

    // wave64 reduce then cross-wave
    #pragma unroll
    for (int off = 32; off > 0; off >>= 1) s += __shfl_down(s, off);
    const int lane = (int)threadIdx.x & 63, wv = (int)threadIdx.x >> 6;
    if (lane == 0) wsum[wv] = s;
    __syncthreads();
    if (threadIdx.x == 0) {
        float t = wsum[0] + wsum[1] + wsum[2] + wsum[3];
        atomicAdd(out, t * (1.0f / ((float)NIMG * IMG_H * IMG_W)));
    }
}

extern "C" void kernel_launch(void* const* d_in, const int* in_sizes, int n_in,
                              void* d_out, int out_size, void* d_ws, size_t ws_size,
                              hipStream_t stream) {
    const float* img = (const float*)d_in[0];
    float* out = (float*)d_out;
    float* rowmax = (float*)d_ws;    // 32*512*512 floats = 33.5 MB scratch

    hipMemsetAsync(d_out, 0, sizeof(float), stream);
    dc_rowmax<<<NIMG * (IMG_H / B_ROWS), 256, 0, stream>>>(img, rowmax);
    dc_colmax<<<NIMG * 16, 256, 0, stream>>>(rowmax, out);
}